// Round 1
// baseline (1091.366 us; speedup 1.0000x reference)
//
#include <hip/hip_runtime.h>
#include <hip/hip_bf16.h>

// Problem constants
constexpr int B = 4, N = 2048, M = 2048, H = 512, KD = 64, ITERS = 20;
constexpr float EPS_IN = 1e-5f;

// ---------------------------------------------------------------------------
// Kernel 1: projections.  qw = [x;y] @ Wq^T + bq  (16384 rows x 64), plus
// per-row squared norms.  Block = 256 threads handles 32 rows; W and X chunks
// staged in LDS (pad 65 to break bank conflicts).
// Block 0 also zeroes the stats area (runs before dist_kernel in stream order).
// ---------------------------------------------------------------------------
__global__ __launch_bounds__(256) void proj_kernel(
    const float* __restrict__ x, const float* __restrict__ y,
    const float* __restrict__ Wq, const float* __restrict__ bq,
    float* __restrict__ qw, float* __restrict__ norms, float* __restrict__ stats) {
  __shared__ float Wl[64][65];
  __shared__ float Xl[32][65];
  int tid = threadIdx.x;
  int r0 = blockIdx.x * 32;  // combined row base (0..16383)
  const float* src = (r0 < B * N) ? x + (size_t)r0 * H
                                  : y + (size_t)(r0 - B * N) * H;
  if (blockIdx.x == 0 && tid < 32) stats[tid] = 0.0f;

  int k = tid & 63;
  float bias = bq[k];
  float acc[8];
#pragma unroll
  for (int c = 0; c < 8; c++) acc[c] = 0.0f;

  for (int hc = 0; hc < H; hc += 64) {
#pragma unroll
    for (int l = 0; l < 16; l++) {
      int idx = tid + l * 256;
      int kk = idx >> 6, hh = idx & 63;
      Wl[kk][hh] = Wq[(size_t)kk * H + hc + hh];
    }
#pragma unroll
    for (int l = 0; l < 8; l++) {
      int idx = tid + l * 256;
      int rr = idx >> 6, hh = idx & 63;
      Xl[rr][hh] = src[(size_t)rr * H + hc + hh];
    }
    __syncthreads();
    int rbase = (tid >> 6) * 8;
#pragma unroll
    for (int hh = 0; hh < 64; hh++) {
      float w = Wl[k][hh];
#pragma unroll
      for (int c = 0; c < 8; c++) acc[c] = fmaf(Xl[rbase + c][hh], w, acc[c]);
    }
    __syncthreads();
  }
  int rbase = (tid >> 6) * 8;
#pragma unroll
  for (int c = 0; c < 8; c++) {
    float v = acc[c] + bias;
    int row = r0 + rbase + c;
    qw[(size_t)row * 64 + k] = v;
    float sq = v * v;
#pragma unroll
    for (int off = 32; off; off >>= 1) sq += __shfl_xor(sq, off, 64);
    if (k == 0) norms[row] = sq;
  }
}

// ---------------------------------------------------------------------------
// Kernel 2: e[b,n,m] = exp(-(|xw_n|^2 + |yw_m|^2 - 2 xw.yw)) written to d_out,
// plus per-batch sum / sumsq / max via block reduction + atomics.
// 64x64 tile per block, 4x4 register micro-tile per thread.
// ---------------------------------------------------------------------------
__global__ __launch_bounds__(256) void dist_kernel(
    const float* __restrict__ qw, const float* __restrict__ norms,
    float* __restrict__ e, float* __restrict__ stats) {
  __shared__ float xt[64][65], yt[64][65];
  __shared__ float xn[64], yn[64];
  int tid = threadIdx.x;
  int b = blockIdx.z;
  int n0 = blockIdx.x * 64, m0 = blockIdx.y * 64;
  const float* xrow = qw + ((size_t)(b * N) + n0) * 64;
  const float* yrow = qw + ((size_t)(B * N + b * M) + m0) * 64;
#pragma unroll
  for (int l = 0; l < 16; l++) {
    int idx = tid + l * 256;
    int r = idx >> 6, kk = idx & 63;
    xt[r][kk] = xrow[(size_t)r * 64 + kk];
    yt[r][kk] = yrow[(size_t)r * 64 + kk];
  }
  if (tid < 64) {
    xn[tid] = norms[b * N + n0 + tid];
    yn[tid] = norms[B * N + b * M + m0 + tid];
  }
  __syncthreads();

  int tx = tid & 15, ty = tid >> 4;
  float acc[4][4] = {};
#pragma unroll
  for (int kk = 0; kk < 64; kk++) {
    float a[4], bb[4];
#pragma unroll
    for (int i = 0; i < 4; i++) a[i] = xt[ty * 4 + i][kk];
#pragma unroll
    for (int j = 0; j < 4; j++) bb[j] = yt[tx * 4 + j][kk];
#pragma unroll
    for (int i = 0; i < 4; i++)
#pragma unroll
      for (int j = 0; j < 4; j++) acc[i][j] = fmaf(a[i], bb[j], acc[i][j]);
  }

  float lsum = 0.0f, lsq = 0.0f, lmax = 0.0f;  // e >= 0
#pragma unroll
  for (int i = 0; i < 4; i++) {
    float4 ev;
    float* evp = (float*)&ev;
    int n = n0 + ty * 4 + i;
#pragma unroll
    for (int j = 0; j < 4; j++) {
      float d = xn[ty * 4 + i] + yn[tx * 4 + j] - 2.0f * acc[i][j];
      float v = __expf(-d);
      evp[j] = v;
      lsum += v;
      lsq += v * v;
      lmax = fmaxf(lmax, v);
    }
    *(float4*)(e + ((size_t)b * N + n) * M + m0 + tx * 4) = ev;
  }

#pragma unroll
  for (int off = 32; off; off >>= 1) {
    lsum += __shfl_xor(lsum, off, 64);
    lsq += __shfl_xor(lsq, off, 64);
    lmax = fmaxf(lmax, __shfl_xor(lmax, off, 64));
  }
  __shared__ float rs[4], rq[4], rm[4];
  int w = tid >> 6, lane = tid & 63;
  if (lane == 0) { rs[w] = lsum; rq[w] = lsq; rm[w] = lmax; }
  __syncthreads();
  if (tid == 0) {
    float ssum = rs[0] + rs[1] + rs[2] + rs[3];
    float ssq = rq[0] + rq[1] + rq[2] + rq[3];
    float smax = fmaxf(fmaxf(rm[0], rm[1]), fmaxf(rm[2], rm[3]));
    atomicAdd(&stats[b * 4 + 0], ssum);
    atomicAdd(&stats[b * 4 + 1], ssq);
    atomicMax((unsigned int*)&stats[b * 4 + 2], __float_as_uint(smax));
  }
}

// ---------------------------------------------------------------------------
// Kernel 3: per-batch affine params.  A = e*s + t.  KK keeps exp args <= 60.
// params[b] = {s, t2 = t - KK, KK, exp(-KK)}
// ---------------------------------------------------------------------------
__global__ void params_kernel(const float* __restrict__ stats,
                              const float* __restrict__ in_w,
                              const float* __restrict__ in_b,
                              float* __restrict__ params) {
  int b = threadIdx.x;
  if (b >= B) return;
  float NMf = (float)N * (float)M;
  float mean = stats[b * 4 + 0] / NMf;
  float var = stats[b * 4 + 1] / NMf - mean * mean;
  var = fmaxf(var, 0.0f);
  float stdv = sqrtf(var + EPS_IN);
  float s = in_w[0] / stdv;
  float t = in_b[0] - mean * s;
  float emax = __uint_as_float(((const unsigned int*)stats)[b * 4 + 2]);
  float Amax = fmaxf(fmaf(s, emax, t), t);  // e in [0, emax]
  float KK = fmaxf(Amax - 60.0f, 0.0f);
  params[b * 4 + 0] = s;
  params[b * 4 + 1] = t - KK;
  params[b * 4 + 2] = KK;
  params[b * 4 + 3] = __expf(-KK);
}

// Init both colsum buffers so that C == 0 for the first row pass.
__global__ void initcol_kernel(const float* __restrict__ params,
                               float* __restrict__ colsum) {
  int j = blockIdx.x * 256 + threadIdx.x;  // over 2*B*M
  int b = (j >> 11) & 3;
  colsum[j] = params[b * 4 + 3];
}

// ---------------------------------------------------------------------------
// Kernel 5: row pass.  R[i] = KK + log(sum_j exp(A - C - KK) + exp(-KK)).
// C recovered lazily from colsum and cached (as t2 - C) in LDS per block.
// Blocks with blockIdx.x < M/256 also reset cs_nxt (ping-pong buffer) to the
// slack-seeded value for the following col pass.
// Block = 256 threads = 4 waves = 4 rows.
// ---------------------------------------------------------------------------
__global__ __launch_bounds__(256) void row_pass(
    const float* __restrict__ e, const float* __restrict__ params,
    const float* __restrict__ cs_cur, float* __restrict__ cs_nxt,
    float* __restrict__ R) {
  __shared__ __align__(16) float C2[M];  // t2 - KK - log(cs)  => arg = fma(e,s,C2)
  int tid = threadIdx.x;
  int b = blockIdx.y;
  float s = params[b * 4 + 0], t2 = params[b * 4 + 1];
  float KK = params[b * 4 + 2], enk = params[b * 4 + 3];
  float cbase = t2 - KK;
#pragma unroll
  for (int l = 0; l < M / 256; l++) {
    int j = l * 256 + tid;
    C2[j] = cbase - __logf(cs_cur[b * M + j]);
  }
  if (blockIdx.x < M / 256) cs_nxt[b * M + blockIdx.x * 256 + tid] = enk;
  __syncthreads();

  int i = blockIdx.x * 4 + (tid >> 6);
  int lane = tid & 63;
  const float* erow = e + ((size_t)b * N + i) * M;
  float s0 = 0.0f, s1 = 0.0f, s2 = 0.0f, s3 = 0.0f;
#pragma unroll
  for (int it = 0; it < M / 256; it++) {
    int j0 = it * 256 + lane * 4;
    float4 ev = *(const float4*)(erow + j0);
    float4 cv = *(const float4*)(&C2[j0]);
    s0 += __expf(fmaf(ev.x, s, cv.x));
    s1 += __expf(fmaf(ev.y, s, cv.y));
    s2 += __expf(fmaf(ev.z, s, cv.z));
    s3 += __expf(fmaf(ev.w, s, cv.w));
  }
  float sum = (s0 + s1) + (s2 + s3);
#pragma unroll
  for (int off = 32; off; off >>= 1) sum += __shfl_xor(sum, off, 64);
  if (lane == 0) R[b * N + i] = KK + __logf(sum + enk);
}

// ---------------------------------------------------------------------------
// Kernel 6: col pass.  Accumulates exp(A - R - KK) into cs_nxt via atomics.
// Block = 256 threads x float4 = 1024 columns, 16-row chunk, coalesced loads.
// ---------------------------------------------------------------------------
__global__ __launch_bounds__(256) void col_pass(
    const float* __restrict__ e, const float* __restrict__ params,
    const float* __restrict__ R, float* __restrict__ cs_nxt) {
  int tid = threadIdx.x;
  int b = blockIdx.z;
  float s = params[b * 4 + 0], t2 = params[b * 4 + 1];
  int j0 = blockIdx.x * 1024 + tid * 4;
  int i0 = blockIdx.y * 16;
  const float* ebase = e + ((size_t)b * N + i0) * M + j0;
  const float* Rb = R + b * N + i0;
  float a0 = 0.0f, a1 = 0.0f, a2 = 0.0f, a3 = 0.0f;
#pragma unroll 4
  for (int ii = 0; ii < 16; ii++) {
    float4 ev = *(const float4*)(ebase + (size_t)ii * M);
    float tt = t2 - Rb[ii];
    a0 += __expf(fmaf(ev.x, s, tt));
    a1 += __expf(fmaf(ev.y, s, tt));
    a2 += __expf(fmaf(ev.z, s, tt));
    a3 += __expf(fmaf(ev.w, s, tt));
  }
  float* cp = cs_nxt + b * M + j0;
  atomicAdd(cp + 0, a0);
  atomicAdd(cp + 1, a1);
  atomicAdd(cp + 2, a2);
  atomicAdd(cp + 3, a3);
}

// ---------------------------------------------------------------------------
// Kernel 7: aw[i] = exp(max_j(A - C) - R).  Same layout as row pass, max
// instead of sum-exp.  mx' computed with the KK-shifted values, KK added back.
// ---------------------------------------------------------------------------
__global__ __launch_bounds__(256) void awmax_kernel(
    const float* __restrict__ e, const float* __restrict__ params,
    const float* __restrict__ cs_cur, const float* __restrict__ R,
    float* __restrict__ aw) {
  __shared__ __align__(16) float C2[M];
  int tid = threadIdx.x;
  int b = blockIdx.y;
  float s = params[b * 4 + 0], t2 = params[b * 4 + 1];
  float KK = params[b * 4 + 2];
  float cbase = t2 - KK;
#pragma unroll
  for (int l = 0; l < M / 256; l++) {
    int j = l * 256 + tid;
    C2[j] = cbase - __logf(cs_cur[b * M + j]);
  }
  __syncthreads();

  int i = blockIdx.x * 4 + (tid >> 6);
  int lane = tid & 63;
  const float* erow = e + ((size_t)b * N + i) * M;
  float mx = -3.4e38f;
#pragma unroll
  for (int it = 0; it < M / 256; it++) {
    int j0 = it * 256 + lane * 4;
    float4 ev = *(const float4*)(erow + j0);
    float4 cv = *(const float4*)(&C2[j0]);
    mx = fmaxf(mx, fmaf(ev.x, s, cv.x));
    mx = fmaxf(mx, fmaf(ev.y, s, cv.y));
    mx = fmaxf(mx, fmaf(ev.z, s, cv.z));
    mx = fmaxf(mx, fmaf(ev.w, s, cv.w));
  }
#pragma unroll
  for (int off = 32; off; off >>= 1) mx = fmaxf(mx, __shfl_xor(mx, off, 64));
  if (lane == 0) aw[b * N + i] = __expf(mx + KK - R[b * N + i]);
}

// ---------------------------------------------------------------------------
// Kernel 8: out[b,n,m] = aw[b,n] * aw[b,m], float4 stores.
// ---------------------------------------------------------------------------
__global__ __launch_bounds__(256) void outer_kernel(const float* __restrict__ aw,
                                                    float* __restrict__ out) {
  size_t idx = (size_t)blockIdx.x * 256 + threadIdx.x;  // B*N*M/4 elements
  int b = (int)(idx >> 20);                             // N*M/4 = 1<<20
  size_t rem = idx & ((1u << 20) - 1);
  int n = (int)(rem >> 9);                              // M/4 = 512
  int m4 = (int)(rem & 511) << 2;
  float a = aw[b * N + n];
  float4 wv = *(const float4*)(aw + b * N + m4);
  float4 o = {a * wv.x, a * wv.y, a * wv.z, a * wv.w};
  *(float4*)(out + (idx << 2)) = o;
}

// ---------------------------------------------------------------------------
extern "C" void kernel_launch(void* const* d_in, const int* in_sizes, int n_in,
                              void* d_out, int out_size, void* d_ws, size_t ws_size,
                              hipStream_t stream) {
  const float* x = (const float*)d_in[0];
  const float* y = (const float*)d_in[1];
  const float* Wq = (const float*)d_in[2];
  const float* bq = (const float*)d_in[3];
  const float* in_w = (const float*)d_in[4];
  const float* in_b = (const float*)d_in[5];
  float* e = (float*)d_out;  // 67 MB scratch for e, overwritten at the end

  float* ws = (float*)d_ws;
  float* qw = ws;                    // 16384 * 64
  float* norms = qw + 1048576;       // 16384
  float* R = norms + 16384;          // 8192
  float* cs0 = R + 8192;             // 8192
  float* cs1 = cs0 + 8192;           // 8192
  float* aw = cs1 + 8192;            // 8192
  float* stats = aw + 8192;          // 32
  float* params = stats + 32;        // 16

  proj_kernel<<<512, 256, 0, stream>>>(x, y, Wq, bq, qw, norms, stats);
  dist_kernel<<<dim3(32, 32, B), 256, 0, stream>>>(qw, norms, e, stats);
  params_kernel<<<1, 64, 0, stream>>>(stats, in_w, in_b, params);
  initcol_kernel<<<64, 256, 0, stream>>>(params, cs0);  // covers cs0 and cs1

  for (int it = 0; it < ITERS; it++) {
    float* cur = (it & 1) ? cs1 : cs0;
    float* nxt = (it & 1) ? cs0 : cs1;
    row_pass<<<dim3(512, B), 256, 0, stream>>>(e, params, cur, nxt, R);
    col_pass<<<dim3(2, 128, B), 256, 0, stream>>>(e, params, R, nxt);
  }
  // ITERS even -> final colsum in cs0, final R from last row pass.
  awmax_kernel<<<dim3(512, B), 256, 0, stream>>>(e, params, cs0, R, aw);
  outer_kernel<<<16384, 256, 0, stream>>>(aw, e);
}

// Round 2
// 747.948 us; speedup vs baseline: 1.4591x; 1.4591x over previous
//
#include <hip/hip_runtime.h>
#include <hip/hip_bf16.h>

// Problem constants
constexpr int B = 4, N = 2048, M = 2048, H = 512, ITERS = 20;
constexpr int ROWS_TOT = B * (N + M);  // 16384
constexpr float EPS_IN = 1e-5f;

// ---------------------------------------------------------------------------
// Kernel 1: projections -> qwT[k][row] (64 x 16384, k-major for dist staging),
// plus per-row squared norms.  Block = 256 threads = 32 rows.  LDS transpose
// for coalesced qwT stores.  Block 0 zeroes the stats area.
// ---------------------------------------------------------------------------
__global__ __launch_bounds__(256) void proj_kernel(
    const float* __restrict__ x, const float* __restrict__ y,
    const float* __restrict__ Wq, const float* __restrict__ bq,
    float* __restrict__ qwT, float* __restrict__ norms, float* __restrict__ stats) {
  __shared__ float Wl[64][65];
  __shared__ float Xl[32][65];
  __shared__ float T[32][65];
  int t = threadIdx.x;
  int r0 = blockIdx.x * 32;  // combined row base (0..16383)
  const float* src = (r0 < B * N) ? x + (size_t)r0 * H
                                  : y + (size_t)(r0 - B * N) * H;
  if (blockIdx.x == 0 && t < 32) stats[t] = 0.0f;

  int k = t & 63;
  float bias = bq[k];
  float acc[8];
#pragma unroll
  for (int c = 0; c < 8; c++) acc[c] = 0.0f;

  for (int hc = 0; hc < H; hc += 64) {
#pragma unroll
    for (int l = 0; l < 16; l++) {
      int idx = t + l * 256;
      int kk = idx >> 6, hh = idx & 63;
      Wl[kk][hh] = Wq[(size_t)kk * H + hc + hh];
    }
#pragma unroll
    for (int l = 0; l < 8; l++) {
      int idx = t + l * 256;
      int rr = idx >> 6, hh = idx & 63;
      Xl[rr][hh] = src[(size_t)rr * H + hc + hh];
    }
    __syncthreads();
    int rbase = (t >> 6) * 8;
#pragma unroll
    for (int hh = 0; hh < 64; hh++) {
      float w = Wl[k][hh];
#pragma unroll
      for (int c = 0; c < 8; c++) acc[c] = fmaf(Xl[rbase + c][hh], w, acc[c]);
    }
    __syncthreads();
  }
  int rbase = (t >> 6) * 8;
#pragma unroll
  for (int c = 0; c < 8; c++) {
    float v = acc[c] + bias;
    T[rbase + c][k] = v;
    float sq = v * v;
#pragma unroll
    for (int off = 32; off; off >>= 1) sq += __shfl_xor(sq, off, 64);
    if (k == 0) norms[r0 + rbase + c] = sq;
  }
  __syncthreads();
#pragma unroll
  for (int p = 0; p < 8; p++) {
    int idx = p * 256 + t;
    int kk = idx >> 5, rr = idx & 31;
    qwT[(size_t)kk * ROWS_TOT + r0 + rr] = T[rr][kk];
  }
}

// ---------------------------------------------------------------------------
// Kernel 2: e[b,n,m] = exp(-(|xw_n|^2 + |yw_m|^2 - 2 xw.yw)) -> d_out, plus
// per-batch sum/sumsq/max.  128x128 tile, k-major LDS, 8x8 microtile,
// ds_read_b128 fragments (<=2-way bank alias).  LDS = exactly 64 KB.
// ---------------------------------------------------------------------------
__global__ __launch_bounds__(256) void dist_kernel(
    const float* __restrict__ qwT, const float* __restrict__ norms,
    float* __restrict__ e, float* __restrict__ stats) {
  __shared__ float xtT[64][128];
  __shared__ float ytT[64][128];
  int t = threadIdx.x;
  int b = blockIdx.z;
  int n0 = blockIdx.x * 128, m0 = blockIdx.y * 128;
  int xbase = b * N + n0;
  int ybase = B * N + b * M + m0;
#pragma unroll
  for (int p = 0; p < 8; p++) {
    int idx = p * 256 + t;
    int kk = idx >> 5, seg = (idx & 31) * 4;
    *(float4*)&xtT[kk][seg] = *(const float4*)(qwT + (size_t)kk * ROWS_TOT + xbase + seg);
    *(float4*)&ytT[kk][seg] = *(const float4*)(qwT + (size_t)kk * ROWS_TOT + ybase + seg);
  }
  __syncthreads();

  int w = t >> 6, lane = t & 63;
  int ri = (w >> 1) * 64 + (lane >> 3) * 8;  // local x-row base (0..120)
  int ci = (w & 1) * 64 + (lane & 7) * 8;    // local y-row base (0..120)

  float acc[8][8] = {};
#pragma unroll 8
  for (int kk = 0; kk < 64; kk++) {
    float4 a0 = *(const float4*)&xtT[kk][ri];
    float4 a1 = *(const float4*)&xtT[kk][ri + 4];
    float4 b0 = *(const float4*)&ytT[kk][ci];
    float4 b1 = *(const float4*)&ytT[kk][ci + 4];
    float av[8] = {a0.x, a0.y, a0.z, a0.w, a1.x, a1.y, a1.z, a1.w};
    float bv[8] = {b0.x, b0.y, b0.z, b0.w, b1.x, b1.y, b1.z, b1.w};
#pragma unroll
    for (int i = 0; i < 8; i++)
#pragma unroll
      for (int j = 0; j < 8; j++) acc[i][j] = fmaf(av[i], bv[j], acc[i][j]);
  }

  // norms for this thread's 8x8 patch (global, L2-hot)
  float4 xnA = *(const float4*)(norms + b * N + n0 + ri);
  float4 xnB = *(const float4*)(norms + b * N + n0 + ri + 4);
  float4 ynA = *(const float4*)(norms + B * N + b * M + m0 + ci);
  float4 ynB = *(const float4*)(norms + B * N + b * M + m0 + ci + 4);
  float xv[8] = {xnA.x, xnA.y, xnA.z, xnA.w, xnB.x, xnB.y, xnB.z, xnB.w};
  float yv[8] = {ynA.x, ynA.y, ynA.z, ynA.w, ynB.x, ynB.y, ynB.z, ynB.w};

  float lsum = 0.0f, lsq = 0.0f, lmax = 0.0f;  // e >= 0
#pragma unroll
  for (int i = 0; i < 8; i++) {
    float o[8];
#pragma unroll
    for (int j = 0; j < 8; j++) {
      float d = xv[i] + yv[j] - 2.0f * acc[i][j];
      float v = __expf(-d);
      o[j] = v;
      lsum += v;
      lsq += v * v;
      lmax = fmaxf(lmax, v);
    }
    size_t row = (size_t)(b * N + n0 + ri + i);
    *(float4*)(e + row * M + m0 + ci) = *(float4*)&o[0];
    *(float4*)(e + row * M + m0 + ci + 4) = *(float4*)&o[4];
  }

#pragma unroll
  for (int off = 32; off; off >>= 1) {
    lsum += __shfl_xor(lsum, off, 64);
    lsq += __shfl_xor(lsq, off, 64);
    lmax = fmaxf(lmax, __shfl_xor(lmax, off, 64));
  }
  __syncthreads();  // done reading tiles; reuse LDS for stat scratch
  float* scr = (float*)xtT;
  if (lane == 0) { scr[w] = lsum; scr[4 + w] = lsq; scr[8 + w] = lmax; }
  __syncthreads();
  if (t == 0) {
    float ssum = scr[0] + scr[1] + scr[2] + scr[3];
    float ssq = scr[4] + scr[5] + scr[6] + scr[7];
    float smax = fmaxf(fmaxf(scr[8], scr[9]), fmaxf(scr[10], scr[11]));
    atomicAdd(&stats[b * 4 + 0], ssum);
    atomicAdd(&stats[b * 4 + 1], ssq);
    atomicMax((unsigned int*)&stats[b * 4 + 2], __float_as_uint(smax));
  }
}

// ---------------------------------------------------------------------------
// Kernel 3: per-batch affine params.  A = e*s + t.  KK keeps exp args <= 60.
// params[b] = {s, t2 = t - KK, KK, exp(-KK)}
// ---------------------------------------------------------------------------
__global__ void params_kernel(const float* __restrict__ stats,
                              const float* __restrict__ in_w,
                              const float* __restrict__ in_b,
                              float* __restrict__ params) {
  int b = threadIdx.x;
  if (b >= B) return;
  float NMf = (float)N * (float)M;
  float mean = stats[b * 4 + 0] / NMf;
  float var = stats[b * 4 + 1] / NMf - mean * mean;
  var = fmaxf(var, 0.0f);
  float stdv = sqrtf(var + EPS_IN);
  float s = in_w[0] / stdv;
  float t = in_b[0] - mean * s;
  float emax = __uint_as_float(((const unsigned int*)stats)[b * 4 + 2]);
  float Amax = fmaxf(fmaf(s, emax, t), t);
  float KK = fmaxf(Amax - 60.0f, 0.0f);
  params[b * 4 + 0] = s;
  params[b * 4 + 1] = t - KK;
  params[b * 4 + 2] = KK;
  params[b * 4 + 3] = __expf(-KK);
}

// C_0 = 0  =>  C2 = t2
__global__ void c2init_kernel(const float* __restrict__ params,
                              float* __restrict__ C2g) {
  int g = blockIdx.x * 256 + threadIdx.x;  // 0..8191
  int b = g >> 11;
  C2g[g] = params[b * 4 + 1];
}

// ---------------------------------------------------------------------------
// Kernel 5: fused sinkhorn pass.  Reads e ONCE: per row computes
// R = KK + log(sum_j exp(fma(e,s,C2)) + enk), then accumulates
// exp(fma(e,s,t2-R)) into per-block column partials.
// Block = 256 threads = 4 waves x 4 rows; lane owns 32 fixed columns.
// ---------------------------------------------------------------------------
__global__ __launch_bounds__(256) void sink_pass(
    const float* __restrict__ e, const float* __restrict__ params,
    const float* __restrict__ C2g, float* __restrict__ R,
    float* __restrict__ partial) {
  __shared__ __align__(16) float colacc[M];
  int t = threadIdx.x;
  int b = blockIdx.y, blk = blockIdx.x;  // blk 0..127
  float s = params[b * 4 + 0], t2 = params[b * 4 + 1];
  float KK = params[b * 4 + 2], enk = params[b * 4 + 3];
  int w = t >> 6, lane = t & 63;

  float c2v[32];
  const float* C2b = C2g + b * M;
#pragma unroll
  for (int it = 0; it < 8; it++) {
    float4 c4 = *(const float4*)(C2b + it * 256 + lane * 4);
    c2v[it * 4 + 0] = c4.x; c2v[it * 4 + 1] = c4.y;
    c2v[it * 4 + 2] = c4.z; c2v[it * 4 + 3] = c4.w;
  }

  int r0 = blk * 16 + w * 4;
  const float* erow = e + ((size_t)b * N + r0) * M;

  // load all 4 rows (128 floats) up front: 32 in-flight b128 loads
  float ev[4][32];
#pragma unroll
  for (int rr = 0; rr < 4; rr++)
#pragma unroll
    for (int it = 0; it < 8; it++) {
      float4 v4 = *(const float4*)(erow + (size_t)rr * M + it * 256 + lane * 4);
      ev[rr][it * 4 + 0] = v4.x; ev[rr][it * 4 + 1] = v4.y;
      ev[rr][it * 4 + 2] = v4.z; ev[rr][it * 4 + 3] = v4.w;
    }

  float acc[32];
#pragma unroll
  for (int q = 0; q < 32; q++) acc[q] = 0.0f;
  float Rv[4];
#pragma unroll
  for (int rr = 0; rr < 4; rr++) {
    float s0 = 0, s1 = 0, s2 = 0, s3 = 0;
#pragma unroll
    for (int it = 0; it < 8; it++) {
      s0 += __expf(fmaf(ev[rr][it * 4 + 0], s, c2v[it * 4 + 0]));
      s1 += __expf(fmaf(ev[rr][it * 4 + 1], s, c2v[it * 4 + 1]));
      s2 += __expf(fmaf(ev[rr][it * 4 + 2], s, c2v[it * 4 + 2]));
      s3 += __expf(fmaf(ev[rr][it * 4 + 3], s, c2v[it * 4 + 3]));
    }
    float sum = (s0 + s1) + (s2 + s3);
#pragma unroll
    for (int off = 32; off; off >>= 1) sum += __shfl_xor(sum, off, 64);
    float Rr = KK + __logf(sum + enk);
    Rv[rr] = Rr;
    float tt = t2 - Rr;
#pragma unroll
    for (int q = 0; q < 32; q++) acc[q] += __expf(fmaf(ev[rr][q], s, tt));
  }
  if (lane == 0) {
#pragma unroll
    for (int rr = 0; rr < 4; rr++) R[b * N + r0 + rr] = Rv[rr];
  }

  // combine the 4 waves' column partials in LDS (disjoint col sets per lane)
  for (int ww = 0; ww < 4; ww++) {
    if (w == ww) {
#pragma unroll
      for (int it = 0; it < 8; it++) {
        int j = it * 256 + lane * 4;
        if (ww == 0) {
          *(float4*)&colacc[j] = *(float4*)&acc[it * 4];
        } else {
          colacc[j + 0] += acc[it * 4 + 0];
          colacc[j + 1] += acc[it * 4 + 1];
          colacc[j + 2] += acc[it * 4 + 2];
          colacc[j + 3] += acc[it * 4 + 3];
        }
      }
    }
    __syncthreads();
  }
  float* pp = partial + ((size_t)b * 128 + blk) * M;
#pragma unroll
  for (int p = 0; p < 2; p++) {
    int j = (p * 256 + t) * 4;
    *(float4*)(pp + j) = *(const float4*)&colacc[j];
  }
}

// ---------------------------------------------------------------------------
// Kernel 6: column reduce.  cs[j] = sum over 128 block partials + enk;
// C2 = t2 - KK - log(cs).  One thread per column, 16-deep ILP.
// ---------------------------------------------------------------------------
__global__ __launch_bounds__(256) void colreduce_kernel(
    const float* __restrict__ partial, const float* __restrict__ params,
    float* __restrict__ C2g) {
  int g = blockIdx.x * 256 + threadIdx.x;  // 0..8191
  int b = g >> 11, j = g & 2047;
  float t2 = params[b * 4 + 1], KK = params[b * 4 + 2], enk = params[b * 4 + 3];
  const float* pb = partial + (size_t)b * 128 * M + j;
  float a[16];
#pragma unroll
  for (int q = 0; q < 16; q++) a[q] = 0.0f;
  for (int k = 0; k < 128; k += 16) {
#pragma unroll
    for (int q = 0; q < 16; q++) a[q] += pb[(size_t)(k + q) * M];
  }
  float cs = 0.0f;
#pragma unroll
  for (int q = 0; q < 16; q++) cs += a[q];
  cs += enk;
  C2g[g] = t2 - KK - __logf(cs);
}

// ---------------------------------------------------------------------------
// Kernel 7: aw[i] = exp(max_j fma(e,s,C2) + KK - R[i]).
// ---------------------------------------------------------------------------
__global__ __launch_bounds__(256) void awmax_kernel(
    const float* __restrict__ e, const float* __restrict__ params,
    const float* __restrict__ C2g, const float* __restrict__ R,
    float* __restrict__ aw) {
  int t = threadIdx.x;
  int b = blockIdx.y, blk = blockIdx.x;
  float s = params[b * 4 + 0], KK = params[b * 4 + 2];
  int w = t >> 6, lane = t & 63;
  float c2v[32];
  const float* C2b = C2g + b * M;
#pragma unroll
  for (int it = 0; it < 8; it++) {
    float4 c4 = *(const float4*)(C2b + it * 256 + lane * 4);
    c2v[it * 4 + 0] = c4.x; c2v[it * 4 + 1] = c4.y;
    c2v[it * 4 + 2] = c4.z; c2v[it * 4 + 3] = c4.w;
  }
  int r0 = blk * 16 + w * 4;
  const float* erow = e + ((size_t)b * N + r0) * M;
#pragma unroll
  for (int rr = 0; rr < 4; rr++) {
    float mx = -3.4e38f;
#pragma unroll
    for (int it = 0; it < 8; it++) {
      float4 v4 = *(const float4*)(erow + (size_t)rr * M + it * 256 + lane * 4);
      mx = fmaxf(mx, fmaf(v4.x, s, c2v[it * 4 + 0]));
      mx = fmaxf(mx, fmaf(v4.y, s, c2v[it * 4 + 1]));
      mx = fmaxf(mx, fmaf(v4.z, s, c2v[it * 4 + 2]));
      mx = fmaxf(mx, fmaf(v4.w, s, c2v[it * 4 + 3]));
    }
#pragma unroll
    for (int off = 32; off; off >>= 1) mx = fmaxf(mx, __shfl_xor(mx, off, 64));
    if (lane == 0) aw[b * N + r0 + rr] = __expf(mx + KK - R[b * N + r0 + rr]);
  }
}

// ---------------------------------------------------------------------------
// Kernel 8: out[b,n,m] = aw[b,n] * aw[b,m], float4 stores.
// ---------------------------------------------------------------------------
__global__ __launch_bounds__(256) void outer_kernel(const float* __restrict__ aw,
                                                    float* __restrict__ out) {
  size_t idx = (size_t)blockIdx.x * 256 + threadIdx.x;  // B*N*M/4 elements
  int b = (int)(idx >> 20);                             // N*M/4 = 1<<20
  size_t rem = idx & ((1u << 20) - 1);
  int n = (int)(rem >> 9);                              // M/4 = 512
  int m4 = (int)(rem & 511) << 2;
  float a = aw[b * N + n];
  float4 wv = *(const float4*)(aw + b * N + m4);
  float4 o = {a * wv.x, a * wv.y, a * wv.z, a * wv.w};
  *(float4*)(out + (idx << 2)) = o;
}

// ---------------------------------------------------------------------------
extern "C" void kernel_launch(void* const* d_in, const int* in_sizes, int n_in,
                              void* d_out, int out_size, void* d_ws, size_t ws_size,
                              hipStream_t stream) {
  const float* x = (const float*)d_in[0];
  const float* y = (const float*)d_in[1];
  const float* Wq = (const float*)d_in[2];
  const float* bq = (const float*)d_in[3];
  const float* in_w = (const float*)d_in[4];
  const float* in_b = (const float*)d_in[5];
  float* e = (float*)d_out;  // 67 MB scratch for e, overwritten at the end

  float* ws = (float*)d_ws;
  float* qwT = ws;                   // 64 * 16384 = 1048576 floats
  float* partial = ws;               // overlay: [B][128][M] = 1048576 (qwT dead)
  float* norms = ws + 1048576;       // 16384
  float* R = norms + 16384;          // 8192
  float* C2 = R + 8192;              // 8192
  float* aw = C2 + 8192;             // 8192
  float* stats = aw + 8192;          // 32
  float* params = stats + 32;        // 16

  proj_kernel<<<512, 256, 0, stream>>>(x, y, Wq, bq, qwT, norms, stats);
  dist_kernel<<<dim3(16, 16, B), 256, 0, stream>>>(qwT, norms, e, stats);
  params_kernel<<<1, 64, 0, stream>>>(stats, in_w, in_b, params);
  c2init_kernel<<<32, 256, 0, stream>>>(params, C2);

  for (int it = 0; it < ITERS; it++) {
    sink_pass<<<dim3(128, B), 256, 0, stream>>>(e, params, C2, R, partial);
    colreduce_kernel<<<32, 256, 0, stream>>>(partial, params, C2);
  }
  awmax_kernel<<<dim3(128, B), 256, 0, stream>>>(e, params, C2, R, aw);
  outer_kernel<<<16384, 256, 0, stream>>>(aw, e);
}

// Round 3
// 581.664 us; speedup vs baseline: 1.8763x; 1.2859x over previous
//
#include <hip/hip_runtime.h>
#include <hip/hip_bf16.h>

// Problem constants
constexpr int B = 4, N = 2048, M = 2048, H = 512, ITERS = 20;
constexpr int ROWS_TOT = B * (N + M);  // 16384
constexpr float EPS_IN = 1e-5f;

// ---------------------------------------------------------------------------
// Kernel 1: projections -> qwT[k][row] (64 x 16384, k-major for dist staging),
// plus per-row squared norms.  Block = 256 threads = 32 rows.  LDS transpose
// for coalesced qwT stores.  Block 0 zeroes the stats area.
// ---------------------------------------------------------------------------
__global__ __launch_bounds__(256) void proj_kernel(
    const float* __restrict__ x, const float* __restrict__ y,
    const float* __restrict__ Wq, const float* __restrict__ bq,
    float* __restrict__ qwT, float* __restrict__ norms, float* __restrict__ stats) {
  __shared__ float Wl[64][65];
  __shared__ float Xl[32][65];
  __shared__ float T[32][65];
  int t = threadIdx.x;
  int r0 = blockIdx.x * 32;  // combined row base (0..16383)
  const float* src = (r0 < B * N) ? x + (size_t)r0 * H
                                  : y + (size_t)(r0 - B * N) * H;
  if (blockIdx.x == 0 && t < 32) stats[t] = 0.0f;

  int k = t & 63;
  float bias = bq[k];
  float acc[8];
#pragma unroll
  for (int c = 0; c < 8; c++) acc[c] = 0.0f;

  for (int hc = 0; hc < H; hc += 64) {
#pragma unroll
    for (int l = 0; l < 16; l++) {
      int idx = t + l * 256;
      int kk = idx >> 6, hh = idx & 63;
      Wl[kk][hh] = Wq[(size_t)kk * H + hc + hh];
    }
#pragma unroll
    for (int l = 0; l < 8; l++) {
      int idx = t + l * 256;
      int rr = idx >> 6, hh = idx & 63;
      Xl[rr][hh] = src[(size_t)rr * H + hc + hh];
    }
    __syncthreads();
    int rbase = (t >> 6) * 8;
#pragma unroll
    for (int hh = 0; hh < 64; hh++) {
      float w = Wl[k][hh];
#pragma unroll
      for (int c = 0; c < 8; c++) acc[c] = fmaf(Xl[rbase + c][hh], w, acc[c]);
    }
    __syncthreads();
  }
  int rbase = (t >> 6) * 8;
#pragma unroll
  for (int c = 0; c < 8; c++) {
    float v = acc[c] + bias;
    T[rbase + c][k] = v;
    float sq = v * v;
#pragma unroll
    for (int off = 32; off; off >>= 1) sq += __shfl_xor(sq, off, 64);
    if (k == 0) norms[r0 + rbase + c] = sq;
  }
  __syncthreads();
#pragma unroll
  for (int p = 0; p < 8; p++) {
    int idx = p * 256 + t;
    int kk = idx >> 5, rr = idx & 31;
    qwT[(size_t)kk * ROWS_TOT + r0 + rr] = T[rr][kk];
  }
}

// ---------------------------------------------------------------------------
// Kernel 2: e[b,n,m] = exp(-(|xw_n|^2 + |yw_m|^2 - 2 xw.yw)) -> d_out, plus
// per-batch sum/sumsq/max.  128x128 tile, k staged in 2x32 chunks (32 KB LDS
// -> 4-5 blocks/CU), 8x8 microtile, ds_read_b128 fragments.
// ---------------------------------------------------------------------------
__global__ __launch_bounds__(256) void dist_kernel(
    const float* __restrict__ qwT, const float* __restrict__ norms,
    float* __restrict__ e, float* __restrict__ stats) {
  __shared__ float xtT[32][128];
  __shared__ float ytT[32][128];
  int t = threadIdx.x;
  int b = blockIdx.z;
  int n0 = blockIdx.x * 128, m0 = blockIdx.y * 128;
  int xbase = b * N + n0;
  int ybase = B * N + b * M + m0;

  int w = t >> 6, lane = t & 63;
  int ri = (w >> 1) * 64 + (lane >> 3) * 8;  // local x-row base (0..120)
  int ci = (w & 1) * 64 + (lane & 7) * 8;    // local y-row base (0..120)

  float acc[8][8] = {};
  for (int kc = 0; kc < 64; kc += 32) {
    if (kc) __syncthreads();
#pragma unroll
    for (int p = 0; p < 4; p++) {
      int idx = p * 256 + t;
      int kk = idx >> 5, seg = (idx & 31) * 4;
      *(float4*)&xtT[kk][seg] =
          *(const float4*)(qwT + (size_t)(kc + kk) * ROWS_TOT + xbase + seg);
      *(float4*)&ytT[kk][seg] =
          *(const float4*)(qwT + (size_t)(kc + kk) * ROWS_TOT + ybase + seg);
    }
    __syncthreads();
#pragma unroll 4
    for (int kk = 0; kk < 32; kk++) {
      float4 a0 = *(const float4*)&xtT[kk][ri];
      float4 a1 = *(const float4*)&xtT[kk][ri + 4];
      float4 b0 = *(const float4*)&ytT[kk][ci];
      float4 b1 = *(const float4*)&ytT[kk][ci + 4];
      float av[8] = {a0.x, a0.y, a0.z, a0.w, a1.x, a1.y, a1.z, a1.w};
      float bv[8] = {b0.x, b0.y, b0.z, b0.w, b1.x, b1.y, b1.z, b1.w};
#pragma unroll
      for (int i = 0; i < 8; i++)
#pragma unroll
        for (int j = 0; j < 8; j++) acc[i][j] = fmaf(av[i], bv[j], acc[i][j]);
    }
  }

  // norms for this thread's 8x8 patch (global, L2-hot)
  float4 xnA = *(const float4*)(norms + b * N + n0 + ri);
  float4 xnB = *(const float4*)(norms + b * N + n0 + ri + 4);
  float4 ynA = *(const float4*)(norms + B * N + b * M + m0 + ci);
  float4 ynB = *(const float4*)(norms + B * N + b * M + m0 + ci + 4);
  float xv[8] = {xnA.x, xnA.y, xnA.z, xnA.w, xnB.x, xnB.y, xnB.z, xnB.w};
  float yv[8] = {ynA.x, ynA.y, ynA.z, ynA.w, ynB.x, ynB.y, ynB.z, ynB.w};

  float lsum = 0.0f, lsq = 0.0f, lmax = 0.0f;  // e >= 0
#pragma unroll
  for (int i = 0; i < 8; i++) {
    float o[8];
#pragma unroll
    for (int j = 0; j < 8; j++) {
      float d = xv[i] + yv[j] - 2.0f * acc[i][j];
      float v = __expf(-d);
      o[j] = v;
      lsum += v;
      lsq += v * v;
      lmax = fmaxf(lmax, v);
    }
    size_t row = (size_t)(b * N + n0 + ri + i);
    *(float4*)(e + row * M + m0 + ci) = *(float4*)&o[0];
    *(float4*)(e + row * M + m0 + ci + 4) = *(float4*)&o[4];
  }

#pragma unroll
  for (int off = 32; off; off >>= 1) {
    lsum += __shfl_xor(lsum, off, 64);
    lsq += __shfl_xor(lsq, off, 64);
    lmax = fmaxf(lmax, __shfl_xor(lmax, off, 64));
  }
  __syncthreads();  // done reading tiles; reuse LDS for stat scratch
  float* scr = (float*)xtT;
  if (lane == 0) { scr[w] = lsum; scr[4 + w] = lsq; scr[8 + w] = lmax; }
  __syncthreads();
  if (t == 0) {
    float ssum = scr[0] + scr[1] + scr[2] + scr[3];
    float ssq = scr[4] + scr[5] + scr[6] + scr[7];
    float smax = fmaxf(fmaxf(scr[8], scr[9]), fmaxf(scr[10], scr[11]));
    atomicAdd(&stats[b * 4 + 0], ssum);
    atomicAdd(&stats[b * 4 + 1], ssq);
    atomicMax((unsigned int*)&stats[b * 4 + 2], __float_as_uint(smax));
  }
}

// ---------------------------------------------------------------------------
// Kernel 3: per-batch affine params.  A = e*s + t.  KK keeps exp args <= 60.
// params[b] = {s, t2 = t - KK, KK, exp(-KK)}
// ---------------------------------------------------------------------------
__global__ void params_kernel(const float* __restrict__ stats,
                              const float* __restrict__ in_w,
                              const float* __restrict__ in_b,
                              float* __restrict__ params) {
  int b = threadIdx.x;
  if (b >= B) return;
  float NMf = (float)N * (float)M;
  float mean = stats[b * 4 + 0] / NMf;
  float var = stats[b * 4 + 1] / NMf - mean * mean;
  var = fmaxf(var, 0.0f);
  float stdv = sqrtf(var + EPS_IN);
  float s = in_w[0] / stdv;
  float t = in_b[0] - mean * s;
  float emax = __uint_as_float(((const unsigned int*)stats)[b * 4 + 2]);
  float Amax = fmaxf(fmaf(s, emax, t), t);
  float KK = fmaxf(Amax - 60.0f, 0.0f);
  params[b * 4 + 0] = s;
  params[b * 4 + 1] = t - KK;
  params[b * 4 + 2] = KK;
  params[b * 4 + 3] = __expf(-KK);
}

// C_0 = 0  =>  C2 = t2; also zero the atomic column accumulator.
__global__ void c2init_kernel(const float* __restrict__ params,
                              float* __restrict__ C2g, float* __restrict__ csacc) {
  int g = blockIdx.x * 256 + threadIdx.x;  // 0..8191
  int b = g >> 11;
  C2g[g] = params[b * 4 + 1];
  csacc[g] = 0.0f;
}

// ---------------------------------------------------------------------------
// Kernel 5: fused sinkhorn pass.  Reads e ONCE: per row computes
// R = KK + log(sum_j exp(fma(e,s,C2)) + enk), then accumulates
// exp(fma(e,s,t2-R)) into per-block column sums -> atomicAdd into csacc.
// Block = 256 threads = 4 waves x 2 rows (sequential); 1024 blocks total.
// C2 staged in LDS to keep VGPRs <= 128 (4 waves/SIMD).
// ---------------------------------------------------------------------------
__global__ __launch_bounds__(256, 4) void sink_pass(
    const float* __restrict__ e, const float* __restrict__ params,
    const float* __restrict__ C2g, float* __restrict__ R,
    float* __restrict__ csacc) {
  __shared__ __align__(16) float C2s[M];     // 8 KB
  __shared__ __align__(16) float colacc[M];  // 8 KB
  int t = threadIdx.x;
  int b = blockIdx.y, blk = blockIdx.x;  // blk 0..255
  float s = params[b * 4 + 0], t2 = params[b * 4 + 1];
  float KK = params[b * 4 + 2], enk = params[b * 4 + 3];
  int w = t >> 6, lane = t & 63;

#pragma unroll
  for (int p = 0; p < 2; p++) {
    int j = (p * 256 + t) * 4;
    *(float4*)&C2s[j] = *(const float4*)(C2g + b * M + j);
  }
  __syncthreads();

  int r0 = blk * 8 + w * 2;
  const float* erow = e + ((size_t)b * N + r0) * M;

  float acc[32];
#pragma unroll
  for (int q = 0; q < 32; q++) acc[q] = 0.0f;
  float Rv[2];

#pragma unroll
  for (int rr = 0; rr < 2; rr++) {
    float ev[32];
#pragma unroll
    for (int it = 0; it < 8; it++) {
      float4 v4 = *(const float4*)(erow + (size_t)rr * M + it * 256 + lane * 4);
      ev[it * 4 + 0] = v4.x; ev[it * 4 + 1] = v4.y;
      ev[it * 4 + 2] = v4.z; ev[it * 4 + 3] = v4.w;
    }
    float s0 = 0, s1 = 0, s2 = 0, s3 = 0;
#pragma unroll
    for (int it = 0; it < 8; it++) {
      int j = it * 256 + lane * 4;
      float4 c4 = *(const float4*)&C2s[j];
      s0 += __expf(fmaf(ev[it * 4 + 0], s, c4.x));
      s1 += __expf(fmaf(ev[it * 4 + 1], s, c4.y));
      s2 += __expf(fmaf(ev[it * 4 + 2], s, c4.z));
      s3 += __expf(fmaf(ev[it * 4 + 3], s, c4.w));
    }
    float sum = (s0 + s1) + (s2 + s3);
#pragma unroll
    for (int off = 32; off; off >>= 1) sum += __shfl_xor(sum, off, 64);
    float Rr = KK + __logf(sum + enk);
    Rv[rr] = Rr;
    float tt = t2 - Rr;
#pragma unroll
    for (int q = 0; q < 32; q++) acc[q] += __expf(fmaf(ev[q], s, tt));
  }
  if (lane == 0) {
    R[b * N + r0 + 0] = Rv[0];
    R[b * N + r0 + 1] = Rv[1];
  }

  // combine the 4 waves' column partials in LDS (disjoint col sets per lane)
  for (int ww = 0; ww < 4; ww++) {
    if (w == ww) {
#pragma unroll
      for (int it = 0; it < 8; it++) {
        int j = it * 256 + lane * 4;
        if (ww == 0) {
          *(float4*)&colacc[j] = *(float4*)&acc[it * 4];
        } else {
          colacc[j + 0] += acc[it * 4 + 0];
          colacc[j + 1] += acc[it * 4 + 1];
          colacc[j + 2] += acc[it * 4 + 2];
          colacc[j + 3] += acc[it * 4 + 3];
        }
      }
    }
    __syncthreads();
  }
#pragma unroll
  for (int p = 0; p < 8; p++) {
    int j = p * 256 + t;
    atomicAdd(&csacc[b * M + j], colacc[j]);
  }
}

// ---------------------------------------------------------------------------
// Kernel 6: C2 = t2 - KK - log(csacc + enk); re-zero csacc for next iter.
// ---------------------------------------------------------------------------
__global__ void c2finish_kernel(float* __restrict__ csacc,
                                const float* __restrict__ params,
                                float* __restrict__ C2g) {
  int g = blockIdx.x * 256 + threadIdx.x;  // 0..8191
  int b = g >> 11;
  float t2 = params[b * 4 + 1], KK = params[b * 4 + 2], enk = params[b * 4 + 3];
  float cs = csacc[g] + enk;
  C2g[g] = t2 - KK - __logf(cs);
  csacc[g] = 0.0f;
}

// ---------------------------------------------------------------------------
// Kernel 7: aw[i] = exp(max_j fma(e,s,C2) + KK - R[i]).
// ---------------------------------------------------------------------------
__global__ __launch_bounds__(256) void awmax_kernel(
    const float* __restrict__ e, const float* __restrict__ params,
    const float* __restrict__ C2g, const float* __restrict__ R,
    float* __restrict__ aw) {
  int t = threadIdx.x;
  int b = blockIdx.y, blk = blockIdx.x;
  float s = params[b * 4 + 0], KK = params[b * 4 + 2];
  int w = t >> 6, lane = t & 63;
  float c2v[32];
  const float* C2b = C2g + b * M;
#pragma unroll
  for (int it = 0; it < 8; it++) {
    float4 c4 = *(const float4*)(C2b + it * 256 + lane * 4);
    c2v[it * 4 + 0] = c4.x; c2v[it * 4 + 1] = c4.y;
    c2v[it * 4 + 2] = c4.z; c2v[it * 4 + 3] = c4.w;
  }
  int r0 = blk * 16 + w * 4;
  const float* erow = e + ((size_t)b * N + r0) * M;
#pragma unroll
  for (int rr = 0; rr < 4; rr++) {
    float mx = -3.4e38f;
#pragma unroll
    for (int it = 0; it < 8; it++) {
      float4 v4 = *(const float4*)(erow + (size_t)rr * M + it * 256 + lane * 4);
      mx = fmaxf(mx, fmaf(v4.x, s, c2v[it * 4 + 0]));
      mx = fmaxf(mx, fmaf(v4.y, s, c2v[it * 4 + 1]));
      mx = fmaxf(mx, fmaf(v4.z, s, c2v[it * 4 + 2]));
      mx = fmaxf(mx, fmaf(v4.w, s, c2v[it * 4 + 3]));
    }
#pragma unroll
    for (int off = 32; off; off >>= 1) mx = fmaxf(mx, __shfl_xor(mx, off, 64));
    if (lane == 0) aw[b * N + r0 + rr] = __expf(mx + KK - R[b * N + r0 + rr]);
  }
}

// ---------------------------------------------------------------------------
// Kernel 8: out[b,n,m] = aw[b,n] * aw[b,m], float4 stores.
// ---------------------------------------------------------------------------
__global__ __launch_bounds__(256) void outer_kernel(const float* __restrict__ aw,
                                                    float* __restrict__ out) {
  size_t idx = (size_t)blockIdx.x * 256 + threadIdx.x;  // B*N*M/4 elements
  int b = (int)(idx >> 20);                             // N*M/4 = 1<<20
  size_t rem = idx & ((1u << 20) - 1);
  int n = (int)(rem >> 9);                              // M/4 = 512
  int m4 = (int)(rem & 511) << 2;
  float a = aw[b * N + n];
  float4 wv = *(const float4*)(aw + b * N + m4);
  float4 o = {a * wv.x, a * wv.y, a * wv.z, a * wv.w};
  *(float4*)(out + (idx << 2)) = o;
}

// ---------------------------------------------------------------------------
extern "C" void kernel_launch(void* const* d_in, const int* in_sizes, int n_in,
                              void* d_out, int out_size, void* d_ws, size_t ws_size,
                              hipStream_t stream) {
  const float* x = (const float*)d_in[0];
  const float* y = (const float*)d_in[1];
  const float* Wq = (const float*)d_in[2];
  const float* bq = (const float*)d_in[3];
  const float* in_w = (const float*)d_in[4];
  const float* in_b = (const float*)d_in[5];
  float* e = (float*)d_out;  // 67 MB scratch for e, overwritten at the end

  float* ws = (float*)d_ws;
  float* qwT = ws;                   // 64 * 16384 = 1048576 floats
  float* norms = ws + 1048576;       // 16384
  float* R = norms + 16384;          // 8192
  float* C2 = R + 8192;              // 8192
  float* csacc = C2 + 8192;          // 8192
  float* aw = csacc + 8192;          // 8192
  float* stats = aw + 8192;          // 32
  float* params = stats + 32;        // 16

  proj_kernel<<<512, 256, 0, stream>>>(x, y, Wq, bq, qwT, norms, stats);
  dist_kernel<<<dim3(16, 16, B), 256, 0, stream>>>(qwT, norms, e, stats);
  params_kernel<<<1, 64, 0, stream>>>(stats, in_w, in_b, params);
  c2init_kernel<<<32, 256, 0, stream>>>(params, C2, csacc);

  for (int it = 0; it < ITERS; it++) {
    sink_pass<<<dim3(256, B), 256, 0, stream>>>(e, params, C2, R, csacc);
    c2finish_kernel<<<32, 256, 0, stream>>>(csacc, params, C2);
  }
  awmax_kernel<<<dim3(128, B), 256, 0, stream>>>(e, params, C2, R, aw);
  outer_kernel<<<16384, 256, 0, stream>>>(aw, e);
}